// Round 7
// baseline (28.189 us; speedup 1.0000x reference)
//
#include <hip/hip_runtime.h>
#include <math.h>

// Problem constants (match reference)
constexpr int   BATCH = 32;
constexpr int   S     = 262144;
constexpr int   BLK   = 128;          // samples per filter block
constexpr int   NB    = S / BLK;      // 2048 blocks per batch row
constexpr float SRATE = 44100.0f;
constexpr float FC_MIN = 2000.0f, FC_MAX = 20000.0f;
constexpr float Q_MIN  = 0.1f,    Q_MAX  = 10.0f;

constexpr int THREADS = 256;
constexpr int GRID    = 2048;                  // one full residency wave
constexpr int TOTAL   = GRID * THREADS;        // 524288 threads
constexpr int UNROLL  = 4;                     // chunks per thread

// 32 lanes per audio block in the coalesced domain (lane r owns samples
// 4r..4r+3 = one float4). No LDS, no barriers. Persistent-style grid:
// each thread handles 4 chunks; ALL 12 global loads issue up front
// (192 B/lane in flight), then 4 independent compute chains interleave.
//
// Biquad as linear state recurrence s' = M s + k x,
//   M = [[-a1, 1], [-a2, 0]]. Pass 1 from zero state yields y_local and
// local end-state u in 16 FMA. Kogge-Stone over the 32-lane segment with
// lane-uniform M^4 powers gives the true incoming state z; output is
// y_n += row0(M^n)·z. Hardware v_sin/v_cos (revolutions): w0/2pi in
// [0.045,0.45], no argument reduction needed.

__global__ __launch_bounds__(THREADS, 4) void lowpass_scan_kernel(
    const float4* __restrict__ x4,
    const float4* __restrict__ cp4,
    float4* __restrict__ o4,
    float* __restrict__ fc_out,
    float* __restrict__ q_out)
{
    const int t0 = blockIdx.x * THREADS + threadIdx.x;
    const int r  = t0 & 31;                    // invariant across chunks

    float4 xv[UNROLL], c0v[UNROLL], c1v[UNROLL];
    int    blkgs[UNROLL];

    // ---- phase 0: issue ALL loads (12 × 16 B per lane, coalesced) --------
#pragma unroll
    for (int u = 0; u < UNROLL; ++u) {
        const int vt   = t0 + u * TOTAL;
        const int blkg = vt >> 5;              // global audio-block id
        const int b    = blkg >> 11;           // batch row
        const int blkL = blkg & (NB - 1);
        blkgs[u] = blkg;
        const size_t xi  = (size_t)blkg * 32 + r;
        const size_t c0i = (size_t)b * (2 * S / 4) + (size_t)blkL * 32 + r;
        xv[u]  = x4[xi];
        c0v[u] = cp4[c0i];
        c1v[u] = cp4[c0i + S / 4];
    }

    // ---- phase 1: 4 independent block computations -----------------------
#pragma unroll
    for (int u = 0; u < UNROLL; ++u) {
        // control means: tree reduce across the 32-lane segment
        float s0 = (c0v[u].x + c0v[u].y) + (c0v[u].z + c0v[u].w);
        float s1 = (c1v[u].x + c1v[u].y) + (c1v[u].z + c1v[u].w);
#pragma unroll
        for (int m = 1; m < 32; m <<= 1) {
            s0 += __shfl_xor(s0, m);
            s1 += __shfl_xor(s1, m);
        }
        const float fc = s0 * (1.0f / BLK) * (FC_MAX - FC_MIN) + FC_MIN;
        const float q  = s1 * (1.0f / BLK) * (Q_MAX - Q_MIN) + Q_MIN;
        if (r == 0) {
            fc_out[blkgs[u]] = fc;
            q_out[blkgs[u]]  = q;
        }

        // RBJ low-pass coefficients (hardware sin/cos, revolutions)
        const float rev = fc * (1.0f / SRATE);
        const float sw = __builtin_amdgcn_sinf(rev);
        const float cw = __builtin_amdgcn_cosf(rev);
        const float alpha = sw / (2.0f * q);
        const float a0inv = 1.0f / (1.0f + alpha);
        const float b0c = (1.0f - cw) * 0.5f * a0inv;   // b2 == b0
        const float b1c = (1.0f - cw) * a0inv;
        const float a1c = (-2.0f * cw) * a0inv;
        const float a2c = (1.0f - alpha) * a0inv;

        // pass 1: DF2T from zero state -> y_local and end-state (z1,z2)
        float z1 = 0.0f, z2 = 0.0f;
        float4 yv;
        {
            float xn, y, z1n;
            xn = xv[u].x; y = b0c * xn + z1;
            z1n = b1c * xn - a1c * y + z2; z2 = b0c * xn - a2c * y; z1 = z1n; yv.x = y;
            xn = xv[u].y; y = b0c * xn + z1;
            z1n = b1c * xn - a1c * y + z2; z2 = b0c * xn - a2c * y; z1 = z1n; yv.y = y;
            xn = xv[u].z; y = b0c * xn + z1;
            z1n = b1c * xn - a1c * y + z2; z2 = b0c * xn - a2c * y; z1 = z1n; yv.z = y;
            xn = xv[u].w; y = b0c * xn + z1;
            z1n = b1c * xn - a1c * y + z2; z2 = b0c * xn - a2c * y; z1 = z1n; yv.w = y;
        }

        // P = M^4 via two squarings of M
        float P00 = -a1c, P01 = 1.0f, P10 = -a2c, P11 = 0.0f;
#define SQUARE_P()                                  \
        {   float q00 = P00 * P00 + P01 * P10;      \
            float q01 = P01 * (P00 + P11);          \
            float q10 = P10 * (P00 + P11);          \
            float q11 = P11 * P11 + P01 * P10;      \
            P00 = q00; P01 = q01; P10 = q10; P11 = q11; }
        SQUARE_P();   // M^2
        SQUARE_P();   // M^4

        // Kogge-Stone inclusive scan over the 32-lane segment
        float v1 = z1, v2 = z2;
#define SCAN_STEP(d)                                        \
        {   float w1 = __shfl_up(v1, d, 32);                \
            float w2 = __shfl_up(v2, d, 32);                \
            float t1 = v1 + P00 * w1 + P01 * w2;            \
            float t2 = v2 + P10 * w1 + P11 * w2;            \
            v1 = (r >= d) ? t1 : v1;                        \
            v2 = (r >= d) ? t2 : v2; }
        SCAN_STEP(1)  SQUARE_P();   // P -> M^8
        SCAN_STEP(2)  SQUARE_P();   // P -> M^16
        SCAN_STEP(4)  SQUARE_P();   // P -> M^32
        SCAN_STEP(8)
        SCAN_STEP(16)
#undef SCAN_STEP
#undef SQUARE_P

        // exclusive shift: incoming state z for this lane's 4 samples
        float zi1 = __shfl_up(v1, 1, 32);
        float zi2 = __shfl_up(v2, 1, 32);
        if (r == 0) { zi1 = 0.0f; zi2 = 0.0f; }

        // output correction: y_n += row0(M^n) · z
        {
            const float c2 = a1c * a1c - a2c;          // a1^2 - a2
            const float c3 = -a1c * c2 + a1c * a2c;    // -a1^3 + 2 a1 a2
            yv.x += zi1;
            yv.y += -a1c * zi1 + zi2;
            yv.z +=   c2 * zi1 - a1c * zi2;
            yv.w +=   c3 * zi1 +   c2 * zi2;
        }
        o4[(size_t)blkgs[u] * 32 + r] = yv;
    }
}

extern "C" void kernel_launch(void* const* d_in, const int* in_sizes, int n_in,
                              void* d_out, int out_size, void* d_ws, size_t ws_size,
                              hipStream_t stream) {
    const float4* x4  = (const float4*)d_in[0];   // (32, 1, 262144)
    const float4* cp4 = (const float4*)d_in[1];   // (32, 2, 262144)

    float* out    = (float*)d_out;                      // 32*262144
    float* fc_out = out + (size_t)BATCH * S;            // 32*2048
    float* q_out  = fc_out + (size_t)BATCH * NB;        // 32*2048

    lowpass_scan_kernel<<<GRID, THREADS, 0, stream>>>(
        x4, cp4, (float4*)out, fc_out, q_out);
}

// Round 8
// 26.876 us; speedup vs baseline: 1.0488x; 1.0488x over previous
//
#include <hip/hip_runtime.h>
#include <math.h>

// Problem constants (match reference)
constexpr int   BATCH = 32;
constexpr int   S     = 262144;
constexpr int   BLK   = 128;          // samples per filter block
constexpr int   NB    = S / BLK;      // 2048 blocks per batch row
constexpr float SRATE = 44100.0f;
constexpr float FC_MIN = 2000.0f, FC_MAX = 20000.0f;
constexpr float Q_MIN  = 0.1f,    Q_MAX  = 10.0f;

constexpr int THREADS = 256;

// 32 lanes per audio block in the coalesced domain (lane r owns samples
// 4r..4r+3 = one float4); each 32-lane segment processes TWO ADJACENT
// blocks, so every stream is a contiguous 4 KB wave-read (page-local,
// fully coalesced) and each thread carries two independent compute chains
// (reduce -> coeffs -> Kogge-Stone scan -> correction) whose shuffle and
// VALU latency interleave. No LDS, no barriers.
//
// Biquad as linear state recurrence s' = M s + k x, M = [[-a1,1],[-a2,0]].
// Pass 1 from zero state yields y_local and local end-state u in 16 FMA.
// Scan with lane-uniform M^4 powers gives the true incoming state z;
// output correction y_n += row0(M^n)·z. Hardware v_sin/v_cos
// (revolutions, w0/2pi in [0.045,0.45] -> no argument reduction).

__global__ __launch_bounds__(THREADS) void lowpass_scan_kernel(
    const float4* __restrict__ x4,
    const float4* __restrict__ cp4,
    float4* __restrict__ o4,
    float* __restrict__ fc_out,
    float* __restrict__ q_out)
{
    const int t0   = blockIdx.x * THREADS + threadIdx.x;
    const int r    = t0 & 31;              // chunk index within a block
    const int seg  = t0 >> 5;              // segment id: handles blocks 2*seg, 2*seg+1
    const int blk0 = seg * 2;              // first audio block of the pair
    const int b    = blk0 >> 11;           // batch row (NB=2048 blocks/row, even)
    const int blkL = blk0 & (NB - 1);

    // float4 indices; the pair spans two contiguous coalesced 2 KB reads
    const size_t xi  = (size_t)blk0 * 32 + r;
    const size_t c0i = (size_t)b * (2 * S / 4) + (size_t)blkL * 32 + r;

    const float4 xvA  = x4[xi];
    const float4 xvB  = x4[xi + 32];
    const float4 c0A  = cp4[c0i];
    const float4 c0B  = cp4[c0i + 32];
    const float4 c1A  = cp4[c0i + S / 4];
    const float4 c1B  = cp4[c0i + S / 4 + 32];

    // ---- control means: two independent segment reductions ---------------
    float s0A = (c0A.x + c0A.y) + (c0A.z + c0A.w);
    float s1A = (c1A.x + c1A.y) + (c1A.z + c1A.w);
    float s0B = (c0B.x + c0B.y) + (c0B.z + c0B.w);
    float s1B = (c1B.x + c1B.y) + (c1B.z + c1B.w);
#pragma unroll
    for (int m = 1; m < 32; m <<= 1) {     // masks <32: stays within segment
        s0A += __shfl_xor(s0A, m);
        s0B += __shfl_xor(s0B, m);
        s1A += __shfl_xor(s1A, m);
        s1B += __shfl_xor(s1B, m);
    }
    const float fcA = s0A * (1.0f / BLK) * (FC_MAX - FC_MIN) + FC_MIN;
    const float qA  = s1A * (1.0f / BLK) * (Q_MAX - Q_MIN) + Q_MIN;
    const float fcB = s0B * (1.0f / BLK) * (FC_MAX - FC_MIN) + FC_MIN;
    const float qB  = s1B * (1.0f / BLK) * (Q_MAX - Q_MIN) + Q_MIN;
    if (r == 0) {
        fc_out[blk0]     = fcA;
        fc_out[blk0 + 1] = fcB;
        q_out[blk0]      = qA;
        q_out[blk0 + 1]  = qB;
    }

    // ---- RBJ coefficients (hardware sin/cos, revolutions) ----------------
    const float revA = fcA * (1.0f / SRATE), revB = fcB * (1.0f / SRATE);
    const float swA = __builtin_amdgcn_sinf(revA), cwA = __builtin_amdgcn_cosf(revA);
    const float swB = __builtin_amdgcn_sinf(revB), cwB = __builtin_amdgcn_cosf(revB);
    const float alA = swA / (2.0f * qA),  alB = swB / (2.0f * qB);
    const float aiA = 1.0f / (1.0f + alA), aiB = 1.0f / (1.0f + alB);
    const float b0A = (1.0f - cwA) * 0.5f * aiA, b0B = (1.0f - cwB) * 0.5f * aiB;
    const float b1A = (1.0f - cwA) * aiA,        b1B = (1.0f - cwB) * aiB;
    const float a1A = (-2.0f * cwA) * aiA,       a1B = (-2.0f * cwB) * aiB;
    const float a2A = (1.0f - alA) * aiA,        a2B = (1.0f - alB) * aiB;

    // ---- pass 1: DF2T from zero state (both blocks, interleavable) -------
    float z1A = 0.0f, z2A = 0.0f, z1B = 0.0f, z2B = 0.0f;
    float4 yA, yB;
#define STEP(xn, yout, b0, b1, a1, a2, z1, z2)              \
    {   float y = b0 * (xn) + z1;                           \
        float z1n = b1 * (xn) - a1 * y + z2;                \
        z2 = b0 * (xn) - a2 * y; z1 = z1n; (yout) = y; }
    STEP(xvA.x, yA.x, b0A, b1A, a1A, a2A, z1A, z2A)
    STEP(xvB.x, yB.x, b0B, b1B, a1B, a2B, z1B, z2B)
    STEP(xvA.y, yA.y, b0A, b1A, a1A, a2A, z1A, z2A)
    STEP(xvB.y, yB.y, b0B, b1B, a1B, a2B, z1B, z2B)
    STEP(xvA.z, yA.z, b0A, b1A, a1A, a2A, z1A, z2A)
    STEP(xvB.z, yB.z, b0B, b1B, a1B, a2B, z1B, z2B)
    STEP(xvA.w, yA.w, b0A, b1A, a1A, a2A, z1A, z2A)
    STEP(xvB.w, yB.w, b0B, b1B, a1B, a2B, z1B, z2B)
#undef STEP

    // ---- P = M^4 via two squarings (both blocks) -------------------------
    float PA00 = -a1A, PA01 = 1.0f, PA10 = -a2A, PA11 = 0.0f;
    float PB00 = -a1B, PB01 = 1.0f, PB10 = -a2B, PB11 = 0.0f;
#define SQUARE(P00, P01, P10, P11)                      \
    {   float q00 = P00 * P00 + P01 * P10;              \
        float q01 = P01 * (P00 + P11);                  \
        float q10 = P10 * (P00 + P11);                  \
        float q11 = P11 * P11 + P01 * P10;              \
        P00 = q00; P01 = q01; P10 = q10; P11 = q11; }
    SQUARE(PA00, PA01, PA10, PA11) SQUARE(PB00, PB01, PB10, PB11)   // M^2
    SQUARE(PA00, PA01, PA10, PA11) SQUARE(PB00, PB01, PB10, PB11)   // M^4

    // ---- two interleaved Kogge-Stone scans -------------------------------
    float vA1 = z1A, vA2 = z2A, vB1 = z1B, vB2 = z2B;
#define SCAN_STEP(d)                                            \
    {   float wA1 = __shfl_up(vA1, d, 32);                      \
        float wB1 = __shfl_up(vB1, d, 32);                      \
        float wA2 = __shfl_up(vA2, d, 32);                      \
        float wB2 = __shfl_up(vB2, d, 32);                      \
        float tA1 = vA1 + PA00 * wA1 + PA01 * wA2;              \
        float tB1 = vB1 + PB00 * wB1 + PB01 * wB2;              \
        float tA2 = vA2 + PA10 * wA1 + PA11 * wA2;              \
        float tB2 = vB2 + PB10 * wB1 + PB11 * wB2;              \
        vA1 = (r >= d) ? tA1 : vA1;  vA2 = (r >= d) ? tA2 : vA2; \
        vB1 = (r >= d) ? tB1 : vB1;  vB2 = (r >= d) ? tB2 : vB2; }
    SCAN_STEP(1)
    SQUARE(PA00, PA01, PA10, PA11) SQUARE(PB00, PB01, PB10, PB11)   // M^8
    SCAN_STEP(2)
    SQUARE(PA00, PA01, PA10, PA11) SQUARE(PB00, PB01, PB10, PB11)   // M^16
    SCAN_STEP(4)
    SQUARE(PA00, PA01, PA10, PA11) SQUARE(PB00, PB01, PB10, PB11)   // M^32
    SCAN_STEP(8)
    SCAN_STEP(16)
#undef SCAN_STEP
#undef SQUARE

    // ---- exclusive shift + output correction (both blocks) ---------------
    float ziA1 = __shfl_up(vA1, 1, 32), ziA2 = __shfl_up(vA2, 1, 32);
    float ziB1 = __shfl_up(vB1, 1, 32), ziB2 = __shfl_up(vB2, 1, 32);
    if (r == 0) { ziA1 = ziA2 = ziB1 = ziB2 = 0.0f; }

    {
        const float c2A = a1A * a1A - a2A;
        const float c3A = -a1A * c2A + a1A * a2A;
        yA.x += ziA1;
        yA.y += -a1A * ziA1 + ziA2;
        yA.z +=   c2A * ziA1 - a1A * ziA2;
        yA.w +=   c3A * ziA1 +  c2A * ziA2;
    }
    {
        const float c2B = a1B * a1B - a2B;
        const float c3B = -a1B * c2B + a1B * a2B;
        yB.x += ziB1;
        yB.y += -a1B * ziB1 + ziB2;
        yB.z +=   c2B * ziB1 - a1B * ziB2;
        yB.w +=   c3B * ziB1 +  c2B * ziB2;
    }
    o4[xi]      = yA;
    o4[xi + 32] = yB;
}

extern "C" void kernel_launch(void* const* d_in, const int* in_sizes, int n_in,
                              void* d_out, int out_size, void* d_ws, size_t ws_size,
                              hipStream_t stream) {
    const float4* x4  = (const float4*)d_in[0];   // (32, 1, 262144)
    const float4* cp4 = (const float4*)d_in[1];   // (32, 2, 262144)

    float* out    = (float*)d_out;                      // 32*262144
    float* fc_out = out + (size_t)BATCH * S;            // 32*2048
    float* q_out  = fc_out + (size_t)BATCH * NB;        // 32*2048

    // 32 lanes per block-PAIR: 32768 segments * 32 lanes = 1,048,576 threads
    const int total_threads = BATCH * NB / 2 * 32;
    lowpass_scan_kernel<<<total_threads / THREADS, THREADS, 0, stream>>>(
        x4, cp4, (float4*)out, fc_out, q_out);
}

// Round 9
// 25.882 us; speedup vs baseline: 1.0891x; 1.0384x over previous
//
#include <hip/hip_runtime.h>
#include <math.h>

// Problem constants (match reference)
constexpr int   BATCH = 32;
constexpr int   S     = 262144;
constexpr int   BLK   = 128;          // samples per filter block
constexpr int   NB    = S / BLK;      // 2048 blocks per batch row
constexpr float SRATE = 44100.0f;
constexpr float FC_MIN = 2000.0f, FC_MAX = 20000.0f;
constexpr float Q_MIN  = 0.1f,    Q_MAX  = 10.0f;

// R5 structure (best measured: 25.68 us). 32 lanes cooperate on one audio
// block IN THE COALESCED DOMAIN (lane r owns samples 4r..4r+3 = one float4).
// No LDS, no barriers, every global transaction coalesced.
//
// Biquad as linear state recurrence: s=(z1,z2), s' = M s + k x with
//   M = [[-a1, 1], [-a2, 0]],  k = (b1 - a1 b0,  b2 - a2 b0)   (b2 == b0)
// Per lane: local 4-sample pass from s=0 gives u_r (block-local end state).
// Kogge-Stone scan over the 32-lane segment with lane-uniform matrix powers
// M^4..M^64 (squared locally, only the 2-float state is shuffled) gives each
// lane its true incoming state; a 4-sample DF2T re-run emits the output.

__global__ __launch_bounds__(256) void lowpass_scan_kernel(
    const float4* __restrict__ x4,
    const float4* __restrict__ cp4,
    float4* __restrict__ o4,
    float* __restrict__ fc_out,
    float* __restrict__ q_out)
{
    const int tid  = blockIdx.x * blockDim.x + threadIdx.x;
    const int r    = tid & 31;             // chunk index within the block
    const int blkg = tid >> 5;             // global audio-block id, 0..65535
    const int b    = blkg >> 11;           // batch row (/ NB)
    const int blkL = blkg & (NB - 1);      // block within batch row

    // float4 indices (all perfectly coalesced across the wave)
    const size_t xi  = (size_t)blkg * 32 + r;                        // x / out
    const size_t c0i = (size_t)b * (2 * S / 4) + (size_t)blkL * 32 + r;

    const float4 xv  = x4[xi];
    const float4 c0v = cp4[c0i];
    const float4 c1v = cp4[c0i + S / 4];

    // ---- control means: tree reduce across the 32-lane segment ----------
    float s0 = (c0v.x + c0v.y) + (c0v.z + c0v.w);
    float s1 = (c1v.x + c1v.y) + (c1v.z + c1v.w);
#pragma unroll
    for (int m = 1; m < 32; m <<= 1) {     // masks <32: stays within segment
        s0 += __shfl_xor(s0, m);
        s1 += __shfl_xor(s1, m);
    }
    const float m0 = s0 * (1.0f / BLK);
    const float m1 = s1 * (1.0f / BLK);

    const float fc = m0 * (FC_MAX - FC_MIN) + FC_MIN;
    const float q  = m1 * (Q_MAX - Q_MIN) + Q_MIN;
    if (r == 0) {                          // one writer per block
        fc_out[blkg] = fc;
        q_out[blkg]  = q;
    }

    // ---- RBJ low-pass coefficients (libm sincos; R5-exact) ---------------
    const float w0 = 6.283185307179586f * fc / SRATE;
    float sw, cw;
    sincosf(w0, &sw, &cw);
    const float alpha = sw / (2.0f * q);
    const float a0inv = 1.0f / (1.0f + alpha);
    const float b0c = (1.0f - cw) * 0.5f * a0inv;   // b2 == b0
    const float b1c = (1.0f - cw) * a0inv;
    const float a1c = (-2.0f * cw) * a0inv;
    const float a2c = (1.0f - alpha) * a0inv;
    const float k1  = b1c - a1c * b0c;
    const float k2  = b0c - a2c * b0c;

    // ---- local pass: 4 samples from zero state -> u = (u1,u2) ------------
    float u1 = 0.0f, u2 = 0.0f;
    {
        float xn, t1;
        xn = xv.x; t1 = u2 - a1c * u1 + k1 * xn; u2 = -a2c * u1 + k2 * xn; u1 = t1;
        xn = xv.y; t1 = u2 - a1c * u1 + k1 * xn; u2 = -a2c * u1 + k2 * xn; u1 = t1;
        xn = xv.z; t1 = u2 - a1c * u1 + k1 * xn; u2 = -a2c * u1 + k2 * xn; u1 = t1;
        xn = xv.w; t1 = u2 - a1c * u1 + k1 * xn; u2 = -a2c * u1 + k2 * xn; u1 = t1;
    }

    // ---- P = M^4 via two squarings of M ----------------------------------
    float P00 = -a1c, P01 = 1.0f, P10 = -a2c, P11 = 0.0f;
#define SQUARE_P()                                  \
    {   float q00 = P00 * P00 + P01 * P10;          \
        float q01 = P01 * (P00 + P11);              \
        float q10 = P10 * (P00 + P11);              \
        float q11 = P11 * P11 + P01 * P10;          \
        P00 = q00; P01 = q01; P10 = q10; P11 = q11; }
    SQUARE_P();   // M^2
    SQUARE_P();   // M^4

    // ---- Kogge-Stone inclusive scan: v_r = sum_{j<=r} P^(r-j) u_j --------
    float v1 = u1, v2 = u2;
#define SCAN_STEP(d)                                        \
    {   float w1 = __shfl_up(v1, d, 32);                    \
        float w2 = __shfl_up(v2, d, 32);                    \
        float t1 = v1 + P00 * w1 + P01 * w2;                \
        float t2 = v2 + P10 * w1 + P11 * w2;                \
        v1 = (r >= d) ? t1 : v1;                            \
        v2 = (r >= d) ? t2 : v2; }
    SCAN_STEP(1)  SQUARE_P();   // P -> M^8
    SCAN_STEP(2)  SQUARE_P();   // P -> M^16
    SCAN_STEP(4)  SQUARE_P();   // P -> M^32
    SCAN_STEP(8)  SQUARE_P();   // P -> M^64
    SCAN_STEP(16)
#undef SCAN_STEP
#undef SQUARE_P

    // ---- exclusive shift: incoming state for this lane's 4 samples -------
    float z1 = __shfl_up(v1, 1, 32);
    float z2 = __shfl_up(v2, 1, 32);
    if (r == 0) { z1 = 0.0f; z2 = 0.0f; }

    // ---- final pass: DF2T with true incoming state, emit y ---------------
    float4 yv;
    {
        float xn, y, z1n;
        xn = xv.x; y = b0c * xn + z1;
        z1n = b1c * xn - a1c * y + z2; z2 = b0c * xn - a2c * y; z1 = z1n; yv.x = y;
        xn = xv.y; y = b0c * xn + z1;
        z1n = b1c * xn - a1c * y + z2; z2 = b0c * xn - a2c * y; z1 = z1n; yv.y = y;
        xn = xv.z; y = b0c * xn + z1;
        z1n = b1c * xn - a1c * y + z2; z2 = b0c * xn - a2c * y; z1 = z1n; yv.z = y;
        xn = xv.w; y = b0c * xn + z1;
        z1n = b1c * xn - a1c * y + z2; z2 = b0c * xn - a2c * y; z1 = z1n; yv.w = y;
    }
    o4[xi] = yv;
}

extern "C" void kernel_launch(void* const* d_in, const int* in_sizes, int n_in,
                              void* d_out, int out_size, void* d_ws, size_t ws_size,
                              hipStream_t stream) {
    const float4* x4  = (const float4*)d_in[0];   // (32, 1, 262144)
    const float4* cp4 = (const float4*)d_in[1];   // (32, 2, 262144)

    float* out    = (float*)d_out;                      // 32*262144
    float* fc_out = out + (size_t)BATCH * S;            // 32*2048
    float* q_out  = fc_out + (size_t)BATCH * NB;        // 32*2048

    // 32 lanes per audio block: 65536 blocks * 32 = 2,097,152 threads
    const int total_threads = BATCH * NB * 32;
    lowpass_scan_kernel<<<total_threads / 256, 256, 0, stream>>>(
        x4, cp4, (float4*)out, fc_out, q_out);
}